// Round 10
// baseline (67.252 us; speedup 1.0000x reference)
//
#include <hip/hip_runtime.h>

#define T_WPAD  962048   // reflect-padded waveform length (before zero tail)
#define T_RAW   960000
#define NFRM    1879
#define OUTW    1876
#define MEDLEN  1864
#define WINL    30
#define PADL    14
#define FPB     8        // frames per block
#define NBX     235      // ceil(NFRM / FPB)
#define XLEN    4296     // 7*512 + 705 + pad (float4-divisible)
#define X4LEN   1074

// ---------------- Kernel 1: NCCF + per-frame lag selection ----------------
// 128 thr = 2 waves; each wave handles FOUR frames (one per 16-lane group).
// g = lane>>4 picks frame-in-wave, s = lane&15 owns lags 12s+1..12s+12.
// Per 4 j-steps the wave issues 2 ds_read_b128 (A broadcast + window advance)
// for 16 frame-steps (48 FMA instrs). Norms computed IN-STREAM (f64 running
// sum of fp32 quad-squares); LDS = signal tile only (17.2 KB). Small blocks
// for CU load balance + latency hiding (1880 blocks, ~15 waves/CU resident).
__global__ __launch_bounds__(128) void nccf_kernel(const float* __restrict__ wav,
                                                   int* __restrict__ idxArr) {
    const int bx   = blockIdx.x;
    const int b    = blockIdx.y;
    const int tid  = threadIdx.x;
    const int wave = tid >> 6;           // 0..1
    const int lane = tid & 63;
    const int g    = lane >> 4;          // frame within wave (0..3)
    const int s    = lane & 15;          // lag-group lane (0..15)

    __shared__ __align__(16) float X[XLEN];

    const long a0 = (long)bx * (FPB * 512);
    const float* wrow = wav + (long)b * T_RAW;

    // Stage wp[a0 .. a0+XLEN): vectorized fast path for interior blocks.
    if (bx >= 1 && bx <= NBX - 2) {
        const float4* src = (const float4*)(wrow + (a0 - 1024));
        float4* dst = (float4*)X;
        for (int i = tid; i < X4LEN; i += 128) dst[i] = src[i];
    } else {
        for (int i = tid; i < XLEN; i += 128) {
            float v = 0.0f;
            long t = a0 + i;
            if (t < T_WPAD) {
                long u = t - 1024;
                if (u < 0) u = -u;
                if (u >= T_RAW) u = 2L * (T_RAW - 1) - u;
                v = wrow[u];
            }
            X[i] = v;
        }
    }
    __syncthreads();

    const int F  = wave * 4 + g;         // frame within block (0..7)
    const int gf = bx * FPB + F;         // global frame
    const bool valid = (gf < NFRM);

    // Main loop: 16-float register window, 12 lags/lane, fp32 dot accum,
    // f64 in-stream sumsq tracking.
    float acc[12];
    #pragma unroll
    for (int r = 0; r < 12; ++r) acc[r] = 0.0f;
    float sq[12];                         // squares of e_0..e_11 (X[12s+j]^2)
    double Tcur = 0.0;                    // running sumsq of lane's stream
    double T512 = 0.0;                    // T(512) = sumsq X[12s .. 12s+512)
    float w[16];

    {
        const float4* X4 = (const float4*)X;
        const int aBase = F * 128;            // float4 index of Xf[0]
        const int wBase = aBase + 3 * s;      // float4 index of Xf[12s]
        #pragma unroll
        for (int d = 0; d < 4; ++d) {
            float4 t4 = X4[wBase + d];
            w[4 * d] = t4.x; w[4 * d + 1] = t4.y; w[4 * d + 2] = t4.z; w[4 * d + 3] = t4.w;
        }
        #pragma unroll
        for (int j = 0; j < 12; ++j) sq[j] = w[j] * w[j];
        // Tcur = T(16): f64 accumulation of the 16 initial squares.
        #pragma unroll
        for (int j = 0; j < 16; ++j) Tcur += (double)(w[j] * w[j]);

        float4 A = X4[aBase];
        // Phase 1: k = 0..123 with T tracking. After iter k, Tcur = T(4k+20).
        #pragma unroll 4
        for (int k = 0; k < 124; ++k) {
            float4 An = X4[aBase + k + 1];    // next A (group-broadcast)
            float4 nx = X4[wBase + k + 4];    // window advance (aligned b128)
            #pragma unroll
            for (int r = 0; r < 12; ++r) {
                acc[r] = fmaf(A.x, w[r + 1], acc[r]);
                acc[r] = fmaf(A.y, w[r + 2], acc[r]);
                acc[r] = fmaf(A.z, w[r + 3], acc[r]);
                acc[r] = fmaf(A.w, w[r + 4], acc[r]);
            }
            float quad = fmaf(nx.x, nx.x, fmaf(nx.y, nx.y, fmaf(nx.z, nx.z, nx.w * nx.w)));
            Tcur += (double)quad;
            #pragma unroll
            for (int i = 0; i < 12; ++i) w[i] = w[i + 4];
            w[12] = nx.x; w[13] = nx.y; w[14] = nx.z; w[15] = nx.w;
            A = An;
        }
        T512 = Tcur;                          // T(512)
        // Phase 2: k = 124..126, no T tracking.
        #pragma unroll
        for (int k = 124; k < 127; ++k) {
            float4 An = X4[aBase + k + 1];
            float4 nx = X4[wBase + k + 4];
            #pragma unroll
            for (int r = 0; r < 12; ++r) {
                acc[r] = fmaf(A.x, w[r + 1], acc[r]);
                acc[r] = fmaf(A.y, w[r + 2], acc[r]);
                acc[r] = fmaf(A.z, w[r + 3], acc[r]);
                acc[r] = fmaf(A.w, w[r + 4], acc[r]);
            }
            #pragma unroll
            for (int i = 0; i < 12; ++i) w[i] = w[i + 4];
            w[12] = nx.x; w[13] = nx.y; w[14] = nx.z; w[15] = nx.w;
            A = An;
        }
        #pragma unroll
        for (int r = 0; r < 12; ++r) {        // last iteration (k=127), no prefetch
            acc[r] = fmaf(A.x, w[r + 1], acc[r]);
            acc[r] = fmaf(A.y, w[r + 2], acc[r]);
            acc[r] = fmaf(A.z, w[r + 3], acc[r]);
            acc[r] = fmaf(A.w, w[r + 4], acc[r]);
        }
    }
    // Window now holds X[12s+508 .. 12s+524): e_{512+i} = w[4+i].

    // Epilogue: per-lag norms from registers.
    //   q(r) = T(512+r) - T(r),  r = 1..12
    double qv[12];
    {
        double Thi = T512, Tlo = 0.0;
        #pragma unroll
        for (int r = 1; r <= 12; ++r) {
            float eh = w[3 + r];              // X[12s+512+(r-1)]
            Thi += (double)(eh * eh);
            Tlo += (double)sq[r - 1];
            qv[r - 1] = Thi - Tlo;
        }
    }
    double s1d = __shfl(T512, 0, 16);         // frame sumsq P[512] (lane s=0)

    // Per-lane selection over its 12 lags (fp32, np-like first-max ties).
    float bestv = -1e30f, halfv = -1e30f;
    int bestk = 1 << 30, halfk = 1 << 30;
    {
        float s1 = 1e-9f + sqrtf((float)s1d);
        float s1n = s1 * s1;
        #pragma unroll
        for (int r = 1; r <= 12; ++r) {
            int lag  = 12 * s + r;
            int kidx = lag - 1;               // nccf lag index 0..191
            if (kidx <= 188) {
                float s2 = 1e-9f + sqrtf((float)qv[r - 1]);
                float v  = acc[r - 1] / s1n / (s2 * s2);
                if (kidx >= 5) {
                    if (v > bestv) { bestv = v; bestk = kidx; }
                    if (kidx <= 93 && v > halfv) { halfv = v; halfk = kidx; }
                }
            }
        }
    }

    // 16-lane (max, first-argmax) reduction for both slices.
    #pragma unroll
    for (int off = 8; off >= 1; off >>= 1) {
        float ov = __shfl_xor(bestv, off, 16); int ok = __shfl_xor(bestk, off, 16);
        if (ov > bestv || (ov == bestv && ok < bestk)) { bestv = ov; bestk = ok; }
        float hv = __shfl_xor(halfv, off, 16); int hk = __shfl_xor(halfk, off, 16);
        if (hv > halfv || (hv == halfv && hk < halfk)) { halfv = hv; halfk = hk; }
    }

    if (valid && s == 0) {
        bool m = (halfv > 0.99f * bestv);
        int sel = m ? halfk : bestk;
        idxArr[b * NFRM + gf] = sel + 1;      // = chosen lag
    }
}

// ---------------- Kernel 2: 30-wide median filter + pitch ----------------
__global__ __launch_bounds__(256) void med_kernel(const int* __restrict__ idxArr,
                                                  float* __restrict__ out) {
    int gid = blockIdx.x * 256 + threadIdx.x;
    if (gid >= 8 * OUTW) return;
    int b = gid / OUTW;
    int i = gid - b * OUTW;
    float o = 0.0f;
    if (i < MEDLEN) {
        const int* row = idxArr + b * NFRM;
        int vals[WINL];
        #pragma unroll
        for (int m = 0; m < WINL; ++m) {
            int sIdx = i + m - PADL;          // left pad = repeat idx[0]
            vals[m] = row[sIdx < 0 ? 0 : sIdx];
        }
        int med = vals[0];
        #pragma unroll
        for (int c = 0; c < WINL; ++c) {
            int cl = 0, ce = 0;
            #pragma unroll
            for (int m = 0; m < WINL; ++m) {
                cl += (vals[m] <  vals[c]) ? 1 : 0;
                ce += (vals[m] == vals[c]) ? 1 : 0;
            }
            if (cl <= 14 && 14 < cl + ce) med = vals[c];   // rank-14 = sorted[14]
        }
        o = 16000.0f / (1e-9f + (float)med);
    }
    out[gid] = o;
}

extern "C" void kernel_launch(void* const* d_in, const int* in_sizes, int n_in,
                              void* d_out, int out_size, void* d_ws, size_t ws_size,
                              hipStream_t stream) {
    const float* wav = (const float*)d_in[0];
    float* out = (float*)d_out;
    int* idxArr = (int*)d_ws;                 // 8*1879 ints = 60128 B

    dim3 gB(NBX, 8);                          // 235 x 8 blocks, 8 frames each
    hipLaunchKernelGGL(nccf_kernel, gB, dim3(128), 0, stream, wav, idxArr);

    int total = 8 * OUTW;
    hipLaunchKernelGGL(med_kernel, dim3((total + 255) / 256), dim3(256), 0, stream,
                       idxArr, out);
}